// Round 3
// baseline (1104.351 us; speedup 1.0000x reference)
//
#include <hip/hip_runtime.h>

#define Bn 128
#define Vn 128000
#define TPB 512
#define NB1 512          // L1 bins: K>>21, K<=0x3F800000 -> bin<=508
#define NB2 512          // L2 sub-bins: bits [20:12]
#define CAP 512          // candidate list capacity per query
#define FMINV -3.4028234663852886e38f   // float32 finfo.min (internal compares only)
#define FOUT  -3.3895313892515355e38f   // 0xFF7F0000: max-finite bf16; avoids +-inf under any bf16 cast

// One block per row. All scratch in LDS; no global workspace used.
__global__ __launch_bounds__(TPB) void sampler_fused(
    const float* __restrict__ logits, const float* __restrict__ temps,
    const int* __restrict__ top_ks, const float* __restrict__ top_ps,
    const float* __restrict__ top_ps2, const float* __restrict__ min_ps,
    const float* __restrict__ uarr,
    float* __restrict__ outTok, float* __restrict__ outLp, float* __restrict__ outNtlp)
{
  __shared__ double   sL1S[NB1];
  __shared__ unsigned sL1C[NB1];
  __shared__ double   sL2S[4*NB2];
  __shared__ unsigned sL2C[4*NB2];
  __shared__ unsigned long long sLists[4*CAP];
  __shared__ unsigned sCnt[8];
  __shared__ float  sRedF[TPB/64];
  __shared__ double sRedD[TPB/64];
  __shared__ float sXm, sZf, sT4, sS2f, sLpTok;
  __shared__ unsigned sThrBits;
  __shared__ unsigned sCutBin[5], sCutPre[5], sCbef[5];
  __shared__ double sSbef[5];
  __shared__ unsigned sV0, sV2;
  __shared__ int sI0, sI2, sQ4mode, sToken;

  const int b = blockIdx.x;
  const int tid = threadIdx.x;
  const float* lrow = logits + (size_t)b * (size_t)Vn;
  const float T = temps[b];

  // ---------- P1a: row max ----------
  float m = -3.4e38f;
  for (int i = tid; i < Vn; i += TPB) m = fmaxf(m, lrow[i]);
  #pragma unroll
  for (int o = 32; o > 0; o >>= 1) m = fmaxf(m, __shfl_down(m, o));
  if ((tid & 63) == 0) sRedF[tid >> 6] = m;
  __syncthreads();
  if (tid == 0) {
    float mm = sRedF[0];
    for (int w = 1; w < TPB/64; ++w) mm = fmaxf(mm, sRedF[w]);
    sXm = mm / T;
  }
  __syncthreads();
  const float xm = sXm;

  // ---------- P1b: Z (f64) ----------
  double z = 0.0;
  for (int i = tid; i < Vn; i += TPB) z += (double)expf(lrow[i]/T - xm);
  #pragma unroll
  for (int o = 32; o > 0; o >>= 1) z += __shfl_down(z, o);
  if ((tid & 63) == 0) sRedD[tid >> 6] = z;
  __syncthreads();
  if (tid == 0) {
    double zz = 0.0;
    for (int w = 0; w < TPB/64; ++w) zz += sRedD[w];
    sZf = (float)zz;
  }
  __syncthreads();
  const float Zf = sZf;

  // ---------- P2: L1 histogram ----------
  for (int i = tid; i < NB1; i += TPB) { sL1S[i] = 0.0; sL1C[i] = 0u; }
  __syncthreads();
  for (int i = tid; i < Vn; i += TPB) {
    float p = expf(lrow[i]/T - xm) / Zf;
    unsigned K = __float_as_uint(p);
    unsigned bin = K >> 21; if (bin > NB1-1) bin = NB1-1;  // defensive, never hit on clean data
    atomicAdd(&sL1S[bin], (double)p);
    atomicAdd(&sL1C[bin], 1u);
  }
  __syncthreads();

  // ---------- P3: L1 walk (thread 0) ----------
  if (tid == 0) {
    float thr = (1.0f / Zf) * min_ps[b];          // p_max = 1/Zf exactly (arg==0 at max elem)
    unsigned thrBits = __float_as_uint(thr);
    sThrBits = thrBits;
    int k = top_ks[b];
    double tauP = (double)top_ps[b], tauP2 = (double)top_ps2[b];
    double S = 0.0; unsigned C = 0;
    int f0 = 0, f1 = 0, f2 = 0;
    int lastBin = -1; unsigned lastC = 0; double lastS = 0.0;
    int thrBin = (int)(thrBits >> 21);
    for (int bin = NB1-1; bin >= 0; --bin) {
      unsigned c = sL1C[bin]; double s = sL1S[bin];
      if (bin == thrBin) { sCutBin[3] = (unsigned)bin; sCbef[3] = C; sSbef[3] = S; }
      if (!c) continue;
      if (!f0 && C + c >= (unsigned)k) { sCutBin[0]=(unsigned)bin; sCbef[0]=C; sSbef[0]=S; f0=1; }
      if (!f1 && S + s > tauP )        { sCutBin[1]=(unsigned)bin; sCbef[1]=C; sSbef[1]=S; f1=1; }
      if (!f2 && S + s > tauP2)        { sCutBin[2]=(unsigned)bin; sCbef[2]=C; sSbef[2]=S; f2=1; }
      lastBin = bin; lastC = C; lastS = S;
      C += c; S += s;
    }
    if (!f1) { sCutBin[1]=(unsigned)lastBin; sCbef[1]=lastC; sSbef[1]=lastS; }
    if (!f2) { sCutBin[2]=(unsigned)lastBin; sCbef[2]=lastC; sSbef[2]=lastS; }
  }
  __syncthreads();

  // ---------- P4: L2 histograms for q0..q3 ----------
  for (int i = tid; i < 4*NB2; i += TPB) { sL2S[i] = 0.0; sL2C[i] = 0u; }
  __syncthreads();
  {
    unsigned tb0 = sCutBin[0], tb1 = sCutBin[1], tb2 = sCutBin[2], tb3 = sCutBin[3];
    for (int i = tid; i < Vn; i += TPB) {
      float p = expf(lrow[i]/T - xm) / Zf;
      unsigned K = __float_as_uint(p);
      unsigned bin = K >> 21, sub = (K >> 12) & (NB2-1);
      if (bin == tb0) { atomicAdd(&sL2S[0*NB2+sub], (double)p); atomicAdd(&sL2C[0*NB2+sub], 1u); }
      if (bin == tb1) { atomicAdd(&sL2S[1*NB2+sub], (double)p); atomicAdd(&sL2C[1*NB2+sub], 1u); }
      if (bin == tb2) { atomicAdd(&sL2S[2*NB2+sub], (double)p); atomicAdd(&sL2C[2*NB2+sub], 1u); }
      if (bin == tb3) { atomicAdd(&sL2S[3*NB2+sub], (double)p); atomicAdd(&sL2C[3*NB2+sub], 1u); }
    }
  }
  __syncthreads();

  // ---------- P5: L2 walk (thread 0) ----------
  if (tid == 0) {
    int k = top_ks[b];
    double tauP = (double)top_ps[b], tauP2 = (double)top_ps2[b];
    int thrSub = (int)((sThrBits >> 12) & (NB2-1));
    for (int q = 0; q < 4; ++q) {
      double S = sSbef[q]; unsigned C = sCbef[q];
      double tau = (q == 1) ? tauP : tauP2;
      int found = 0, lastSub = -1; unsigned lastC = 0; double lastS = 0.0;
      for (int sub = NB2-1; sub >= 0; --sub) {
        unsigned c = sL2C[q*NB2+sub]; double s = sL2S[q*NB2+sub];
        if (q == 3 && sub == thrSub) { sCutPre[3]=(sCutBin[3]<<9)|(unsigned)sub; sCbef[3]=C; sSbef[3]=S; found=1; break; }
        if (!c) continue;
        if (q == 0) {
          if (C + c >= (unsigned)k) { sCutPre[0]=(sCutBin[0]<<9)|(unsigned)sub; sCbef[0]=C; sSbef[0]=S; found=1; break; }
        } else if (q < 3) {
          if (S + s > tau) { sCutPre[q]=(sCutBin[q]<<9)|(unsigned)sub; sCbef[q]=C; sSbef[q]=S; found=1; break; }
        }
        lastSub = sub; lastC = C; lastS = S;
        C += c; S += s;
      }
      if (!found && q != 3 && lastSub >= 0) {
        sCutPre[q]=(sCutBin[q]<<9)|(unsigned)lastSub; sCbef[q]=lastC; sSbef[q]=lastS;
      }
    }
    for (int q = 0; q < 5; ++q) sCnt[q] = 0u;
  }
  __syncthreads();

  // ---------- P6: collect boundary candidates for q0..q3 ----------
  {
    unsigned t0 = sCutPre[0], t1 = sCutPre[1], t2 = sCutPre[2], t3 = sCutPre[3];
    for (int i = tid; i < Vn; i += TPB) {
      float p = expf(lrow[i]/T - xm) / Zf;
      unsigned K = __float_as_uint(p);
      unsigned pre = K >> 12;
      unsigned long long e = (((unsigned long long)(~K)) << 32) | (unsigned)i;
      if (pre == t0) { unsigned pos = atomicAdd(&sCnt[0], 1u); if (pos < CAP) sLists[0*CAP+pos] = e; }
      if (pre == t1) { unsigned pos = atomicAdd(&sCnt[1], 1u); if (pos < CAP) sLists[1*CAP+pos] = e; }
      if (pre == t2) { unsigned pos = atomicAdd(&sCnt[2], 1u); if (pos < CAP) sLists[2*CAP+pos] = e; }
      if (pre == t3) { unsigned pos = atomicAdd(&sCnt[3], 1u); if (pos < CAP) sLists[3*CAP+pos] = e; }
    }
  }
  __syncthreads();

  // ---------- P7: resolve boundaries, total, t4, q4 L1 walk (thread 0) ----------
  if (tid == 0) {
    int k = top_ks[b];
    double tauP = (double)top_ps[b], tauP2 = (double)top_ps2[b];
    unsigned vS[4]; int iS[4]; double sk[4];
    for (int q = 0; q < 4; ++q) {
      int n = (int)sCnt[q]; if (n > CAP) n = CAP;
      unsigned long long* L = &sLists[q*CAP];
      for (int i2 = 1; i2 < n; ++i2) {               // sort: p desc, idx asc
        unsigned long long key = L[i2]; int j = i2-1;
        while (j >= 0 && L[j] > key) { L[j+1] = L[j]; --j; }
        L[j+1] = key;
      }
      double S = sSbef[q];
      if (q == 0) {
        if (n > 0) {
          int mm = k - (int)sCbef[0]; if (mm < 1) mm = 1; if (mm > n) mm = n;
          for (int j = 0; j < mm; ++j) { unsigned K = ~(unsigned)(L[j] >> 32); S += (double)__uint_as_float(K); }
          unsigned long long e = L[mm-1];
          vS[0] = ~(unsigned)(e >> 32); iS[0] = (int)(unsigned)(e & 0xFFFFFFFFu); sk[0] = S;
        } else { vS[0] = 0u; iS[0] = 0x7FFFFFFF; sk[0] = S; }
      } else if (q < 3) {
        double tau = (q == 1) ? tauP : tauP2;
        int last = -1;
        for (int j = 0; j < n; ++j) {
          if (S > tau) break;
          unsigned K = ~(unsigned)(L[j] >> 32);
          S += (double)__uint_as_float(K); last = j;
        }
        if (n > 0) {
          int pick = (last < 0) ? 0 : last;
          unsigned long long e = L[pick];
          vS[q] = ~(unsigned)(e >> 32); iS[q] = (int)(unsigned)(e & 0xFFFFFFFFu); sk[q] = S;
        } else { vS[q] = 0u; iS[q] = 0x7FFFFFFF; sk[q] = S; }
      } else {
        unsigned thrB = sThrBits;
        for (int j = 0; j < n; ++j) {
          unsigned K = ~(unsigned)(L[j] >> 32);
          if (K < thrB) break;
          S += (double)__uint_as_float(K);
        }
        vS[3] = thrB; iS[3] = 0x7FFFFFFF; sk[3] = S;
      }
    }
    // most restrictive of {top_k, top_p, min_p}
    unsigned v0 = vS[0]; int i0 = iS[0]; double tot = sk[0];
    if (vS[1] > v0 || (vS[1] == v0 && iS[1] < i0)) { v0 = vS[1]; i0 = iS[1]; tot = sk[1]; }
    if (vS[3] > v0 || (vS[3] == v0 && iS[3] < i0)) { v0 = vS[3]; i0 = iS[3]; tot = sk[3]; }
    sV0 = v0; sI0 = i0;
    sV2 = vS[2]; sI2 = iS[2]; sS2f = (float)sk[2];
    float totalF = (float)tot;
    float t4 = uarr[b] * totalF;
    sT4 = t4;
    // q4 (sampling) L1 walk — sL1S/sL1C still live
    double S = 0.0; unsigned C = 0; double t4d = (double)t4; int found = 0;
    for (int bin = NB1-1; bin >= 0; --bin) {
      unsigned c = sL1C[bin]; if (!c) continue;
      double s = sL1S[bin];
      if (S + s >= t4d) { sCutBin[4]=(unsigned)bin; sCbef[4]=C; sSbef[4]=S; found=1; break; }
      C += c; S += s;
    }
    if (!found) { sQ4mode = 2; sToken = i0; }
    else sQ4mode = 0;
  }
  __syncthreads();

  // ---------- P8..P10: q4 refinement (uniform branch) ----------
  {
    int q4m = sQ4mode;            // block-uniform
    if (q4m == 0) {
      for (int i = tid; i < NB2; i += TPB) { sL2S[i] = 0.0; sL2C[i] = 0u; }
      __syncthreads();
      unsigned tb = sCutBin[4];
      for (int i = tid; i < Vn; i += TPB) {
        float p = expf(lrow[i]/T - xm) / Zf;
        unsigned K = __float_as_uint(p);
        if ((K >> 21) == tb) {
          unsigned sub = (K >> 12) & (NB2-1);
          atomicAdd(&sL2S[sub], (double)p); atomicAdd(&sL2C[sub], 1u);
        }
      }
      __syncthreads();
      if (tid == 0) {
        double S = sSbef[4]; unsigned C = sCbef[4]; double t4d = (double)sT4;
        int found = 0, lastSub = -1; unsigned lastC = 0; double lastS = 0.0;
        for (int sub = NB2-1; sub >= 0; --sub) {
          unsigned c = sL2C[sub]; if (!c) continue;
          double s = sL2S[sub];
          if (S + s >= t4d) { sCutPre[4]=(sCutBin[4]<<9)|(unsigned)sub; sCbef[4]=C; sSbef[4]=S; found=1; break; }
          lastSub = sub; lastC = C; lastS = S; C += c; S += s;
        }
        if (!found) {
          if (lastSub < 0) { sQ4mode = 2; sToken = sI0; }
          else { sCutPre[4]=(sCutBin[4]<<9)|(unsigned)lastSub; sCbef[4]=lastC; sSbef[4]=lastS; }
        }
      }
      __syncthreads();
      int q4m2 = sQ4mode;         // block-uniform
      if (q4m2 == 0) {
        unsigned t4p = sCutPre[4];
        for (int i = tid; i < Vn; i += TPB) {
          float p = expf(lrow[i]/T - xm) / Zf;
          unsigned K = __float_as_uint(p);
          if ((K >> 12) == t4p) {
            unsigned pos = atomicAdd(&sCnt[4], 1u);
            if (pos < CAP) sLists[pos] = (((unsigned long long)(~K)) << 32) | (unsigned)i;
          }
        }
      }
      __syncthreads();
    }
  }

  // ---------- P11: pick token + its logprob (thread 0) ----------
  if (tid == 0) {
    int token; unsigned pB;
    if (sQ4mode == 2) { token = sToken; pB = sV0; }
    else {
      int n = (int)sCnt[4]; if (n > CAP) n = CAP;
      unsigned long long* L = sLists;
      for (int i2 = 1; i2 < n; ++i2) {
        unsigned long long key = L[i2]; int j = i2-1;
        while (j >= 0 && L[j] > key) { L[j+1] = L[j]; --j; }
        L[j+1] = key;
      }
      double S = sSbef[4], t4d = (double)sT4;
      unsigned v0 = sV0; int i0 = sI0;
      token = -1; pB = sV0;
      for (int j = 0; j < n; ++j) {
        unsigned K = ~(unsigned)(L[j] >> 32);
        int idx = (int)(unsigned)(L[j] & 0xFFFFFFFFu);
        bool kept = (K > v0) || (K == v0 && idx <= i0);
        if (!kept) { token = i0; pB = v0; break; }
        S += (double)__uint_as_float(K);
        if (S >= t4d) { token = idx; pB = K; break; }
      }
      if (token < 0) { token = i0; pB = v0; }
    }
    unsigned v2 = sV2; int i2 = sI2;
    bool kept2 = (pB > v2) || (pB == v2 && token <= i2);
    float pt = __uint_as_float(pB);
    float lp = kept2 ? fmaxf(logf(pt / sS2f), FMINV) : FOUT;
    sToken = token; sLpTok = lp;
  }
  __syncthreads();

  // ---------- P12: write logprobs row + scalars ----------
  {
    unsigned v2 = sV2; int i2 = sI2; float S2f = sS2f;
    float* orow = outLp + (size_t)b * (size_t)Vn;
    for (int i = tid; i < Vn; i += TPB) {
      float p = expf(lrow[i]/T - xm) / Zf;
      unsigned K = __float_as_uint(p);
      float o = FOUT;
      if (K > v2 || (K == v2 && i <= i2)) o = fmaxf(logf(p / S2f), FMINV);
      orow[i] = o;
    }
    if (tid == 0) { outTok[b] = (float)sToken; outNtlp[b] = sLpTok; }
  }
}

extern "C" void kernel_launch(void* const* d_in, const int* in_sizes, int n_in,
                              void* d_out, int out_size, void* d_ws, size_t ws_size,
                              hipStream_t stream)
{
  const float* logits  = (const float*)d_in[0];
  const float* temps   = (const float*)d_in[1];
  const int*   top_ks  = (const int*)d_in[2];
  const float* top_ps  = (const float*)d_in[3];
  const float* top_ps2 = (const float*)d_in[4];
  const float* min_ps  = (const float*)d_in[5];
  const float* uarr    = (const float*)d_in[6];

  float* outTok  = (float*)d_out;                  // token_ids (as float), 128
  float* outLp   = outTok + Bn;                    // logprobs, 128*128000
  float* outNtlp = outLp + (size_t)Bn * Vn;        // next_token_logprobs, 128

  sampler_fused<<<Bn, TPB, 0, stream>>>(logits, temps, top_ks, top_ps, top_ps2,
                                        min_ps, uarr, outTok, outLp, outNtlp);
}

// Round 4
// 810.110 us; speedup vs baseline: 1.3632x; 1.3632x over previous
//
#include <hip/hip_runtime.h>

#define Bn 128
#define Vn 128000
#define SLICES 8
#define SLICE_LEN 16000      // Vn/SLICES, divisible by 4
#define TPB 256
#define NB1 512              // L1 bins: K>>21 (p<=1 -> bin<=508)
#define NB2 512              // L2 sub-bins: K bits [20:12]
#define CAP 512
#define FMINV -3.4028234663852886e38f   // internal clamp (matches ref finfo.min)
#define FOUT  -3.3895313892515355e38f   // 0xFF7F0000 max-finite-bf16 for masked outputs

// ---- ws arena (bytes); total ~7.43 MB (round-1 proved >=16 MB usable) ----
#define OFF_ROWS   0u
#define OFF_SLICEM 65536u
#define OFF_SLICEZ 73728u
#define OFF_L1S    81920u          // f64 [128][512]   512 KB
#define OFF_L1C    606208u         // u32 [128][512]   256 KB
#define OFF_L2S    868352u         // f64 [128][5][512] 2.62 MB
#define OFF_L2C    3489792u        // u32 [128][5][512] 1.31 MB
#define OFF_LCNT   4800512u        // u32 [128][8]
#define OFF_LISTS  4804608u        // u64 [128][5][512] 2.62 MB
#define ZERO_U64   600576u         // zero [0, OFF_LISTS)

struct RowWS {
  float A, Zf, S2f, t4, lpTok;
  unsigned thrBits;
  int q4mode, token;
  unsigned v0; int i0; unsigned v2; int i2;
  unsigned cutBin[5], cutPre[5], Cbef[5];
  double Sbef[5];
};

__global__ void k_zero(unsigned long long* p){
  size_t i = (size_t)blockIdx.x*TPB + threadIdx.x;
  size_t st = (size_t)gridDim.x*TPB;
  for (; i < ZERO_U64; i += st) p[i] = 0ull;
}

// ---- pass 1: per-slice max + exp-sum (slice-local offset) ----
__global__ __launch_bounds__(TPB) void k_maxz(const float* __restrict__ logits,
    const float* __restrict__ temps, float* sliceM, double* sliceZ){
  __shared__ float  sF[TPB/64];
  __shared__ double sD[TPB/64];
  __shared__ float  sMax;
  int blk = blockIdx.x, b = blk >> 3, sl = blk & 7, tid = threadIdx.x;
  const float4* l4 = (const float4*)(logits + (size_t)b*Vn + sl*SLICE_LEN);
  float m = -3.4e38f;
  for (int j = tid; j < SLICE_LEN/4; j += TPB){
    float4 v = l4[j];
    m = fmaxf(m, fmaxf(fmaxf(v.x, v.y), fmaxf(v.z, v.w)));
  }
  #pragma unroll
  for (int o = 32; o; o >>= 1) m = fmaxf(m, __shfl_down(m, o));
  if ((tid & 63) == 0) sF[tid >> 6] = m;
  __syncthreads();
  if (tid == 0){ float mm = sF[0]; for (int w = 1; w < TPB/64; ++w) mm = fmaxf(mm, sF[w]); sMax = mm; }
  __syncthreads();
  float T = temps[b];
  float a = sMax / T;
  double z = 0.0;
  for (int j = tid; j < SLICE_LEN/4; j += TPB){
    float4 v = l4[j];
    z += (double)expf(v.x/T - a) + (double)expf(v.y/T - a)
       + (double)expf(v.z/T - a) + (double)expf(v.w/T - a);
  }
  #pragma unroll
  for (int o = 32; o; o >>= 1) z += __shfl_down(z, o);
  if ((tid & 63) == 0) sD[tid >> 6] = z;
  __syncthreads();
  if (tid == 0){
    double zz = 0.0; for (int w = 0; w < TPB/64; ++w) zz += sD[w];
    sliceM[b*SLICES + sl] = sMax;
    sliceZ[b*SLICES + sl] = zz;
  }
}

// ---- combine slice stats -> A (=M/T), Zf ----
__global__ void k_combine(const float* __restrict__ temps, const float* sliceM,
                          const double* sliceZ, RowWS* rows){
  int b = blockIdx.x;
  if (threadIdx.x) return;
  float T = temps[b];
  float M = sliceM[b*SLICES];
  for (int s = 1; s < SLICES; ++s) M = fmaxf(M, sliceM[b*SLICES + s]);
  float A = M / T;
  double Z = 0.0;
  for (int s = 0; s < SLICES; ++s)
    Z += sliceZ[b*SLICES + s] * exp((double)(sliceM[b*SLICES + s] / T) - (double)A);
  rows[b].A = A; rows[b].Zf = (float)Z;
}

// ---- pass 2: compute K once, cache to Kc, build L1 histogram ----
__global__ __launch_bounds__(TPB) void k_l1hist(const float* __restrict__ logits,
    const float* __restrict__ temps, const RowWS* __restrict__ rows,
    double* L1S, unsigned* L1C, unsigned* __restrict__ Kc){
  __shared__ double   hS[4*NB1];
  __shared__ unsigned hC[4*NB1];
  int blk = blockIdx.x, b = blk >> 3, sl = blk & 7, tid = threadIdx.x;
  int cp = (tid >> 6) & 3;
  for (int i = tid; i < 4*NB1; i += TPB){ hS[i] = 0.0; hC[i] = 0u; }
  float T = temps[b], A = rows[b].A, Zf = rows[b].Zf;
  __syncthreads();
  size_t base = (size_t)b*Vn + sl*SLICE_LEN;
  const float4* l4 = (const float4*)(logits + base);
  uint4* K4 = (uint4*)(Kc + base);
  for (int j = tid; j < SLICE_LEN/4; j += TPB){
    float4 v = l4[j];
    uint4 kk;
    float p0 = expf(v.x/T - A) / Zf; kk.x = __float_as_uint(p0);
    float p1 = expf(v.y/T - A) / Zf; kk.y = __float_as_uint(p1);
    float p2 = expf(v.z/T - A) / Zf; kk.z = __float_as_uint(p2);
    float p3 = expf(v.w/T - A) / Zf; kk.w = __float_as_uint(p3);
    unsigned b0 = min(kk.x >> 21, NB1-1u), b1 = min(kk.y >> 21, NB1-1u);
    unsigned b2 = min(kk.z >> 21, NB1-1u), b3 = min(kk.w >> 21, NB1-1u);
    unsafeAtomicAdd(&hS[cp*NB1 + b0], (double)p0); atomicAdd(&hC[cp*NB1 + b0], 1u);
    unsafeAtomicAdd(&hS[cp*NB1 + b1], (double)p1); atomicAdd(&hC[cp*NB1 + b1], 1u);
    unsafeAtomicAdd(&hS[cp*NB1 + b2], (double)p2); atomicAdd(&hC[cp*NB1 + b2], 1u);
    unsafeAtomicAdd(&hS[cp*NB1 + b3], (double)p3); atomicAdd(&hC[cp*NB1 + b3], 1u);
    K4[j] = kk;
  }
  __syncthreads();
  for (int bin = tid; bin < NB1; bin += TPB){
    unsigned c = hC[bin] + hC[NB1+bin] + hC[2*NB1+bin] + hC[3*NB1+bin];
    if (c){
      double s = hS[bin] + hS[NB1+bin] + hS[2*NB1+bin] + hS[3*NB1+bin];
      unsafeAtomicAdd(&L1S[(size_t)b*NB1 + bin], s);
      atomicAdd(&L1C[(size_t)b*NB1 + bin], c);
    }
  }
}

// ---- L1 walk (serial per row; rows parallel) ----
__global__ void k_l1walk(RowWS* rows, const double* L1S, const unsigned* L1C,
    const int* __restrict__ top_ks, const float* __restrict__ top_ps,
    const float* __restrict__ top_ps2, const float* __restrict__ min_ps){
  int b = blockIdx.x;
  if (threadIdx.x) return;
  RowWS& R = rows[b];
  float thr = (1.0f / R.Zf) * min_ps[b];
  unsigned thrBits = __float_as_uint(thr);
  R.thrBits = thrBits;
  int k = top_ks[b];
  double tauP = (double)top_ps[b], tauP2 = (double)top_ps2[b];
  const double* S1 = L1S + (size_t)b*NB1;
  const unsigned* C1 = L1C + (size_t)b*NB1;
  double S = 0.0; unsigned C = 0;
  int f0=0, f1=0, f2=0, lastBin=-1; unsigned lastC=0; double lastS=0.0;
  int thrBin = (int)(thrBits >> 21);
  for (int bin = NB1-1; bin >= 0; --bin){
    unsigned c = C1[bin]; double s = S1[bin];
    if (bin == thrBin){ R.cutBin[3]=(unsigned)bin; R.Cbef[3]=C; R.Sbef[3]=S; }
    if (!c) continue;
    if (!f0 && C + c >= (unsigned)k){ R.cutBin[0]=(unsigned)bin; R.Cbef[0]=C; R.Sbef[0]=S; f0=1; }
    if (!f1 && S + s > tauP ){ R.cutBin[1]=(unsigned)bin; R.Cbef[1]=C; R.Sbef[1]=S; f1=1; }
    if (!f2 && S + s > tauP2){ R.cutBin[2]=(unsigned)bin; R.Cbef[2]=C; R.Sbef[2]=S; f2=1; }
    lastBin = bin; lastC = C; lastS = S;
    C += c; S += s;
  }
  if (!f1){ R.cutBin[1]=(unsigned)lastBin; R.Cbef[1]=lastC; R.Sbef[1]=lastS; }
  if (!f2){ R.cutBin[2]=(unsigned)lastBin; R.Cbef[2]=lastC; R.Sbef[2]=lastS; }
}

// ---- pass 3: L2 histograms for q0..q3 (reads K only) ----
__global__ __launch_bounds__(TPB) void k_l2hist(const unsigned* __restrict__ Kc,
    const RowWS* __restrict__ rows, double* L2S, unsigned* L2C){
  __shared__ double   hS[4*NB2];
  __shared__ unsigned hC[4*NB2];
  int blk = blockIdx.x, b = blk >> 3, sl = blk & 7, tid = threadIdx.x;
  for (int i = tid; i < 4*NB2; i += TPB){ hS[i] = 0.0; hC[i] = 0u; }
  unsigned tb0 = rows[b].cutBin[0], tb1 = rows[b].cutBin[1];
  unsigned tb2 = rows[b].cutBin[2], tb3 = rows[b].cutBin[3];
  __syncthreads();
  const uint4* K4 = (const uint4*)(Kc + (size_t)b*Vn + sl*SLICE_LEN);
  for (int j = tid; j < SLICE_LEN/4; j += TPB){
    uint4 kk = K4[j];
    #pragma unroll
    for (int c = 0; c < 4; ++c){
      unsigned K = (c==0)?kk.x:(c==1)?kk.y:(c==2)?kk.z:kk.w;
      unsigned bin = K >> 21, sub = (K >> 12) & (NB2-1);
      double p = (double)__uint_as_float(K);
      if (bin == tb0){ unsafeAtomicAdd(&hS[0*NB2+sub], p); atomicAdd(&hC[0*NB2+sub], 1u); }
      if (bin == tb1){ unsafeAtomicAdd(&hS[1*NB2+sub], p); atomicAdd(&hC[1*NB2+sub], 1u); }
      if (bin == tb2){ unsafeAtomicAdd(&hS[2*NB2+sub], p); atomicAdd(&hC[2*NB2+sub], 1u); }
      if (bin == tb3){ unsafeAtomicAdd(&hS[3*NB2+sub], p); atomicAdd(&hC[3*NB2+sub], 1u); }
    }
  }
  __syncthreads();
  for (int i = tid; i < 4*NB2; i += TPB){
    if (hC[i]){
      unsafeAtomicAdd(&L2S[((size_t)b*5)*NB2 + i], hS[i]);
      atomicAdd(&L2C[((size_t)b*5)*NB2 + i], hC[i]);
    }
  }
}

// ---- L2 walk ----
__global__ void k_l2walk(RowWS* rows, const double* L2S, const unsigned* L2C,
    const int* __restrict__ top_ks, const float* __restrict__ top_ps,
    const float* __restrict__ top_ps2){
  int b = blockIdx.x;
  if (threadIdx.x) return;
  RowWS& R = rows[b];
  int k = top_ks[b];
  int thrSub = (int)((R.thrBits >> 12) & (NB2-1));
  for (int q = 0; q < 4; ++q){
    const double* S2 = L2S + ((size_t)b*5 + q)*NB2;
    const unsigned* C2 = L2C + ((size_t)b*5 + q)*NB2;
    double S = R.Sbef[q]; unsigned C = R.Cbef[q];
    double tau = (q == 1) ? (double)top_ps[b] : (double)top_ps2[b];
    int found = 0, lastSub = -1; unsigned lastC = 0; double lastS = 0.0;
    for (int sub = NB2-1; sub >= 0; --sub){
      unsigned c = C2[sub]; double s = S2[sub];
      if (q == 3 && sub == thrSub){ R.cutPre[3]=(R.cutBin[3]<<9)|(unsigned)sub; R.Cbef[3]=C; R.Sbef[3]=S; found=1; break; }
      if (!c) continue;
      if (q == 0){
        if (C + c >= (unsigned)k){ R.cutPre[0]=(R.cutBin[0]<<9)|(unsigned)sub; R.Cbef[0]=C; R.Sbef[0]=S; found=1; break; }
      } else if (q < 3){
        if (S + s > tau){ R.cutPre[q]=(R.cutBin[q]<<9)|(unsigned)sub; R.Cbef[q]=C; R.Sbef[q]=S; found=1; break; }
      }
      lastSub = sub; lastC = C; lastS = S;
      C += c; S += s;
    }
    if (!found && q != 3 && lastSub >= 0){
      R.cutPre[q]=(R.cutBin[q]<<9)|(unsigned)lastSub; R.Cbef[q]=lastC; R.Sbef[q]=lastS;
    }
  }
}

// ---- pass 4: collect boundary candidates q0..q3 ----
__global__ __launch_bounds__(TPB) void k_collect(const unsigned* __restrict__ Kc,
    const RowWS* __restrict__ rows, unsigned long long* lists, unsigned* lcnt){
  int blk = blockIdx.x, b = blk >> 3, sl = blk & 7, tid = threadIdx.x;
  unsigned t0 = rows[b].cutPre[0], t1 = rows[b].cutPre[1];
  unsigned t2 = rows[b].cutPre[2], t3 = rows[b].cutPre[3];
  int base = sl*SLICE_LEN;
  const uint4* K4 = (const uint4*)(Kc + (size_t)b*Vn + base);
  for (int j = tid; j < SLICE_LEN/4; j += TPB){
    uint4 kk = K4[j];
    #pragma unroll
    for (int c = 0; c < 4; ++c){
      unsigned K = (c==0)?kk.x:(c==1)?kk.y:(c==2)?kk.z:kk.w;
      unsigned pre = K >> 12;
      if (pre != t0 && pre != t1 && pre != t2 && pre != t3) continue;
      int i = base + j*4 + c;
      unsigned long long e = (((unsigned long long)(~K)) << 32) | (unsigned)i;
      if (pre == t0){ unsigned pos = atomicAdd(&lcnt[b*8+0], 1u); if (pos < CAP) lists[((size_t)b*5+0)*CAP+pos] = e; }
      if (pre == t1){ unsigned pos = atomicAdd(&lcnt[b*8+1], 1u); if (pos < CAP) lists[((size_t)b*5+1)*CAP+pos] = e; }
      if (pre == t2){ unsigned pos = atomicAdd(&lcnt[b*8+2], 1u); if (pos < CAP) lists[((size_t)b*5+2)*CAP+pos] = e; }
      if (pre == t3){ unsigned pos = atomicAdd(&lcnt[b*8+3], 1u); if (pos < CAP) lists[((size_t)b*5+3)*CAP+pos] = e; }
    }
  }
}

// ---- resolve boundaries + q4 L1 walk ----
__global__ void k_resolve(RowWS* rows, const unsigned long long* lists, const unsigned* lcnt,
    const double* L1S, const unsigned* L1C,
    const int* __restrict__ top_ks, const float* __restrict__ top_ps,
    const float* __restrict__ top_ps2, const float* __restrict__ uarr){
  __shared__ unsigned long long Ls[4*CAP];
  int b = blockIdx.x, tid = threadIdx.x;
  int nq[4];
  for (int q = 0; q < 4; ++q){
    int n = (int)lcnt[b*8+q]; if (n > CAP) n = CAP; nq[q] = n;
    for (int j = tid; j < n; j += 64) Ls[q*CAP+j] = lists[((size_t)b*5+q)*CAP + j];
  }
  __syncthreads();
  if (tid) return;
  RowWS& R = rows[b];
  int k = top_ks[b];
  double tauP = (double)top_ps[b], tauP2 = (double)top_ps2[b];
  unsigned vS[4]; int iS[4]; double sk[4];
  for (int q = 0; q < 4; ++q){
    int n = nq[q];
    unsigned long long* L = &Ls[q*CAP];
    for (int i2 = 1; i2 < n; ++i2){
      unsigned long long key = L[i2]; int j = i2-1;
      while (j >= 0 && L[j] > key){ L[j+1] = L[j]; --j; }
      L[j+1] = key;
    }
    double S = R.Sbef[q];
    if (q == 0){
      if (n > 0){
        int mm = k - (int)R.Cbef[0]; if (mm < 1) mm = 1; if (mm > n) mm = n;
        for (int j = 0; j < mm; ++j){ unsigned K = ~(unsigned)(L[j] >> 32); S += (double)__uint_as_float(K); }
        unsigned long long e = L[mm-1];
        vS[0] = ~(unsigned)(e >> 32); iS[0] = (int)(unsigned)(e & 0xFFFFFFFFu); sk[0] = S;
      } else { vS[0] = 0u; iS[0] = 0x7FFFFFFF; sk[0] = S; }
    } else if (q < 3){
      double tau = (q == 1) ? tauP : tauP2;
      int last = -1;
      for (int j = 0; j < n; ++j){
        if (S > tau) break;
        unsigned K = ~(unsigned)(L[j] >> 32);
        S += (double)__uint_as_float(K); last = j;
      }
      if (n > 0){
        int pick = (last < 0) ? 0 : last;
        unsigned long long e = L[pick];
        vS[q] = ~(unsigned)(e >> 32); iS[q] = (int)(unsigned)(e & 0xFFFFFFFFu); sk[q] = S;
      } else { vS[q] = 0u; iS[q] = 0x7FFFFFFF; sk[q] = S; }
    } else {
      unsigned thrB = R.thrBits;
      for (int j = 0; j < n; ++j){
        unsigned K = ~(unsigned)(L[j] >> 32);
        if (K < thrB) break;
        S += (double)__uint_as_float(K);
      }
      vS[3] = thrB; iS[3] = 0x7FFFFFFF; sk[3] = S;
    }
  }
  unsigned v0 = vS[0]; int i0 = iS[0]; double tot = sk[0];
  if (vS[1] > v0 || (vS[1] == v0 && iS[1] < i0)){ v0 = vS[1]; i0 = iS[1]; tot = sk[1]; }
  if (vS[3] > v0 || (vS[3] == v0 && iS[3] < i0)){ v0 = vS[3]; i0 = iS[3]; tot = sk[3]; }
  R.v0 = v0; R.i0 = i0;
  R.v2 = vS[2]; R.i2 = iS[2]; R.S2f = (float)sk[2];
  float t4 = uarr[b] * (float)tot;
  R.t4 = t4;
  const double* S1 = L1S + (size_t)b*NB1;
  const unsigned* C1 = L1C + (size_t)b*NB1;
  double S = 0.0; unsigned C = 0; double t4d = (double)t4; int found = 0;
  for (int bin = NB1-1; bin >= 0; --bin){
    unsigned c = C1[bin]; if (!c) continue;
    double s = S1[bin];
    if (S + s >= t4d){ R.cutBin[4]=(unsigned)bin; R.Cbef[4]=C; R.Sbef[4]=S; found=1; break; }
    C += c; S += s;
  }
  if (!found){ R.q4mode = 2; R.token = i0; }
  else R.q4mode = 0;
}

// ---- pass 5: q4 L2 histogram ----
__global__ __launch_bounds__(TPB) void k_q4hist(const unsigned* __restrict__ Kc,
    const RowWS* __restrict__ rows, double* L2S, unsigned* L2C){
  __shared__ double   hS[NB2];
  __shared__ unsigned hC[NB2];
  int blk = blockIdx.x, b = blk >> 3, sl = blk & 7, tid = threadIdx.x;
  if (rows[b].q4mode == 2) return;
  for (int i = tid; i < NB2; i += TPB){ hS[i] = 0.0; hC[i] = 0u; }
  unsigned tb = rows[b].cutBin[4];
  __syncthreads();
  const uint4* K4 = (const uint4*)(Kc + (size_t)b*Vn + sl*SLICE_LEN);
  for (int j = tid; j < SLICE_LEN/4; j += TPB){
    uint4 kk = K4[j];
    #pragma unroll
    for (int c = 0; c < 4; ++c){
      unsigned K = (c==0)?kk.x:(c==1)?kk.y:(c==2)?kk.z:kk.w;
      if ((K >> 21) == tb){
        unsigned sub = (K >> 12) & (NB2-1);
        unsafeAtomicAdd(&hS[sub], (double)__uint_as_float(K)); atomicAdd(&hC[sub], 1u);
      }
    }
  }
  __syncthreads();
  for (int i = tid; i < NB2; i += TPB){
    if (hC[i]){
      unsafeAtomicAdd(&L2S[((size_t)b*5 + 4)*NB2 + i], hS[i]);
      atomicAdd(&L2C[((size_t)b*5 + 4)*NB2 + i], hC[i]);
    }
  }
}

__global__ void k_q4walk(RowWS* rows, const double* L2S, const unsigned* L2C){
  int b = blockIdx.x;
  if (threadIdx.x) return;
  RowWS& R = rows[b];
  if (R.q4mode == 2) return;
  const double* S2 = L2S + ((size_t)b*5 + 4)*NB2;
  const unsigned* C2 = L2C + ((size_t)b*5 + 4)*NB2;
  double S = R.Sbef[4]; unsigned C = R.Cbef[4]; double t4d = (double)R.t4;
  int found = 0, lastSub = -1; unsigned lastC = 0; double lastS = 0.0;
  for (int sub = NB2-1; sub >= 0; --sub){
    unsigned c = C2[sub]; if (!c) continue;
    double s = S2[sub];
    if (S + s >= t4d){ R.cutPre[4]=(R.cutBin[4]<<9)|(unsigned)sub; R.Cbef[4]=C; R.Sbef[4]=S; found=1; break; }
    lastSub = sub; lastC = C; lastS = S; C += c; S += s;
  }
  if (!found){
    if (lastSub < 0){ R.q4mode = 2; R.token = R.i0; }
    else { R.cutPre[4]=(R.cutBin[4]<<9)|(unsigned)lastSub; R.Cbef[4]=lastC; R.Sbef[4]=lastS; }
  }
}

// ---- pass 6: q4 collect ----
__global__ __launch_bounds__(TPB) void k_q4collect(const unsigned* __restrict__ Kc,
    const RowWS* __restrict__ rows, unsigned long long* lists, unsigned* lcnt){
  int blk = blockIdx.x, b = blk >> 3, sl = blk & 7, tid = threadIdx.x;
  if (rows[b].q4mode == 2) return;
  unsigned t4p = rows[b].cutPre[4];
  int base = sl*SLICE_LEN;
  const uint4* K4 = (const uint4*)(Kc + (size_t)b*Vn + base);
  for (int j = tid; j < SLICE_LEN/4; j += TPB){
    uint4 kk = K4[j];
    #pragma unroll
    for (int c = 0; c < 4; ++c){
      unsigned K = (c==0)?kk.x:(c==1)?kk.y:(c==2)?kk.z:kk.w;
      if ((K >> 12) == t4p){
        unsigned pos = atomicAdd(&lcnt[b*8+4], 1u);
        if (pos < CAP) lists[((size_t)b*5+4)*CAP + pos] = (((unsigned long long)(~K)) << 32) | (unsigned)(base + j*4 + c);
      }
    }
  }
}

__global__ void k_pick(RowWS* rows, const unsigned long long* lists, const unsigned* lcnt){
  __shared__ unsigned long long Ls[CAP];
  int b = blockIdx.x, tid = threadIdx.x;
  RowWS& R = rows[b];
  int n = (int)lcnt[b*8+4]; if (n > CAP) n = CAP;
  if (R.q4mode != 2)
    for (int j = tid; j < n; j += 64) Ls[j] = lists[((size_t)b*5+4)*CAP + j];
  __syncthreads();
  if (tid) return;
  int token; unsigned pB;
  if (R.q4mode == 2){ token = R.token; pB = R.v0; }
  else {
    for (int i2 = 1; i2 < n; ++i2){
      unsigned long long key = Ls[i2]; int j = i2-1;
      while (j >= 0 && Ls[j] > key){ Ls[j+1] = Ls[j]; --j; }
      Ls[j+1] = key;
    }
    double S = R.Sbef[4], t4d = (double)R.t4;
    unsigned v0 = R.v0; int i0 = R.i0;
    token = -1; pB = R.v0;
    for (int j = 0; j < n; ++j){
      unsigned K = ~(unsigned)(Ls[j] >> 32);
      int idx = (int)(unsigned)(Ls[j] & 0xFFFFFFFFu);
      bool kept = (K > v0) || (K == v0 && idx <= i0);
      if (!kept){ token = i0; pB = v0; break; }
      S += (double)__uint_as_float(K);
      if (S >= t4d){ token = idx; pB = K; break; }
    }
    if (token < 0){ token = i0; pB = v0; }
  }
  unsigned v2 = R.v2; int i2 = R.i2;
  bool kept2 = (pB > v2) || (pB == v2 && token <= i2);
  float pt = __uint_as_float(pB);
  float lp = kept2 ? fmaxf(logf(pt / R.S2f), FMINV) : FOUT;
  R.token = token; R.lpTok = lp;
}

// ---- pass 7: write logprobs (overwrites K-cache in place) + scalars ----
__global__ __launch_bounds__(TPB) void k_out(const RowWS* __restrict__ rows,
    float* __restrict__ outTok, float* __restrict__ outLp, float* __restrict__ outNtlp){
  int blk = blockIdx.x, b = blk >> 3, sl = blk & 7, tid = threadIdx.x;
  unsigned v2 = rows[b].v2; int i2 = rows[b].i2; float S2f = rows[b].S2f;
  int base = sl*SLICE_LEN;
  float4* O4 = (float4*)(outLp + (size_t)b*Vn + base);
  const uint4* K4 = (const uint4*)O4;   // same region: read K, write logprob
  for (int j = tid; j < SLICE_LEN/4; j += TPB){
    uint4 kk = K4[j];
    float4 o;
    #pragma unroll
    for (int c = 0; c < 4; ++c){
      unsigned K = (c==0)?kk.x:(c==1)?kk.y:(c==2)?kk.z:kk.w;
      int i = base + j*4 + c;
      float p = __uint_as_float(K);
      float val = (K > v2 || (K == v2 && i <= i2)) ? fmaxf(logf(p / S2f), FMINV) : FOUT;
      if (c==0) o.x = val; else if (c==1) o.y = val; else if (c==2) o.z = val; else o.w = val;
    }
    O4[j] = o;
  }
  if (sl == 0 && tid == 0){ outTok[b] = (float)rows[b].token; outNtlp[b] = rows[b].lpTok; }
}

extern "C" void kernel_launch(void* const* d_in, const int* in_sizes, int n_in,
                              void* d_out, int out_size, void* d_ws, size_t ws_size,
                              hipStream_t stream)
{
  const float* logits  = (const float*)d_in[0];
  const float* temps   = (const float*)d_in[1];
  const int*   top_ks  = (const int*)d_in[2];
  const float* top_ps  = (const float*)d_in[3];
  const float* top_ps2 = (const float*)d_in[4];
  const float* min_ps  = (const float*)d_in[5];
  const float* uarr    = (const float*)d_in[6];

  char* ws = (char*)d_ws;
  RowWS*    rows   = (RowWS*)(ws + OFF_ROWS);
  float*    sliceM = (float*)(ws + OFF_SLICEM);
  double*   sliceZ = (double*)(ws + OFF_SLICEZ);
  double*   L1S    = (double*)(ws + OFF_L1S);
  unsigned* L1C    = (unsigned*)(ws + OFF_L1C);
  double*   L2S    = (double*)(ws + OFF_L2S);
  unsigned* L2C    = (unsigned*)(ws + OFF_L2C);
  unsigned* lcnt   = (unsigned*)(ws + OFF_LCNT);
  unsigned long long* lists = (unsigned long long*)(ws + OFF_LISTS);

  float* outTok  = (float*)d_out;
  float* outLp   = outTok + Bn;
  float* outNtlp = outLp + (size_t)Bn * Vn;
  unsigned* Kc   = (unsigned*)outLp;     // K-cache lives in the big output buffer

  const int G = Bn * SLICES;             // 1024 blocks for heavy passes
  k_zero     <<<1024, TPB, 0, stream>>>((unsigned long long*)ws);
  k_maxz     <<<G,    TPB, 0, stream>>>(logits, temps, sliceM, sliceZ);
  k_combine  <<<Bn,   64,  0, stream>>>(temps, sliceM, sliceZ, rows);
  k_l1hist   <<<G,    TPB, 0, stream>>>(logits, temps, rows, L1S, L1C, Kc);
  k_l1walk   <<<Bn,   64,  0, stream>>>(rows, L1S, L1C, top_ks, top_ps, top_ps2, min_ps);
  k_l2hist   <<<G,    TPB, 0, stream>>>(Kc, rows, L2S, L2C);
  k_l2walk   <<<Bn,   64,  0, stream>>>(rows, L2S, L2C, top_ks, top_ps, top_ps2);
  k_collect  <<<G,    TPB, 0, stream>>>(Kc, rows, lists, lcnt);
  k_resolve  <<<Bn,   64,  0, stream>>>(rows, lists, lcnt, L1S, L1C, top_ks, top_ps, top_ps2, uarr);
  k_q4hist   <<<G,    TPB, 0, stream>>>(Kc, rows, L2S, L2C);
  k_q4walk   <<<Bn,   64,  0, stream>>>(rows, L2S, L2C);
  k_q4collect<<<G,    TPB, 0, stream>>>(Kc, rows, lists, lcnt);
  k_pick     <<<Bn,   64,  0, stream>>>(rows, lists, lcnt);
  k_out      <<<G,    TPB, 0, stream>>>(rows, outTok, outLp, outNtlp);
}

// Round 5
// 259.698 us; speedup vs baseline: 4.2524x; 3.1194x over previous
//
#include <hip/hip_runtime.h>

#define Bn 128
#define Vn 128000
#define SLICES 8
#define SLICE_LEN 16000      // Vn/SLICES, divisible by 4
#define TPB 256
#define WTPB 512             // walk kernels: one thread per bin
#define NB1 512              // L1 bins: K>>21 (p<=1 -> bin<=508)
#define NB2 512              // L2 sub-bins: K bits [20:12]
#define CAP 512
#define FMINV -3.4028234663852886e38f   // internal clamp (matches ref finfo.min)
#define FOUT  -3.3895313892515355e38f   // 0xFF7F0000 max-finite-bf16 for masked outputs

// ---- ws arena (bytes) ----
#define OFF_ROWS   0u
#define OFF_SLICEM 65536u
#define OFF_SLICEZ 73728u
#define OFF_L1S    81920u
#define OFF_L1C    606208u
#define OFF_L2S    868352u
#define OFF_L2C    3489792u
#define OFF_LCNT   4800512u
#define OFF_LISTS  4804608u
#define ZERO_U64   600576u         // zero [0, OFF_LISTS)

struct RowWS {
  float A, Zf, S2f, t4, lpTok;
  unsigned thrBits;
  int q4mode, token;
  unsigned v0; int i0; unsigned v2; int i2;
  unsigned cutBin[5], cutPre[5], Cbef[5];
  double Sbef[5];
};

__global__ void k_zero(unsigned long long* p){
  size_t i = (size_t)blockIdx.x*TPB + threadIdx.x;
  size_t st = (size_t)gridDim.x*TPB;
  for (; i < ZERO_U64; i += st) p[i] = 0ull;
}

// ---- pass 1: per-slice max + exp-sum ----
__global__ __launch_bounds__(TPB) void k_maxz(const float* __restrict__ logits,
    const float* __restrict__ temps, float* sliceM, double* sliceZ){
  __shared__ float  sF[TPB/64];
  __shared__ double sD[TPB/64];
  __shared__ float  sMax;
  int blk = blockIdx.x, b = blk >> 3, sl = blk & 7, tid = threadIdx.x;
  const float4* l4 = (const float4*)(logits + (size_t)b*Vn + sl*SLICE_LEN);
  float m = -3.4e38f;
  for (int j = tid; j < SLICE_LEN/4; j += TPB){
    float4 v = l4[j];
    m = fmaxf(m, fmaxf(fmaxf(v.x, v.y), fmaxf(v.z, v.w)));
  }
  #pragma unroll
  for (int o = 32; o; o >>= 1) m = fmaxf(m, __shfl_down(m, o));
  if ((tid & 63) == 0) sF[tid >> 6] = m;
  __syncthreads();
  if (tid == 0){ float mm = sF[0]; for (int w = 1; w < TPB/64; ++w) mm = fmaxf(mm, sF[w]); sMax = mm; }
  __syncthreads();
  float T = temps[b];
  float a = sMax / T;
  double z = 0.0;
  for (int j = tid; j < SLICE_LEN/4; j += TPB){
    float4 v = l4[j];
    z += (double)expf(v.x/T - a) + (double)expf(v.y/T - a)
       + (double)expf(v.z/T - a) + (double)expf(v.w/T - a);
  }
  #pragma unroll
  for (int o = 32; o; o >>= 1) z += __shfl_down(z, o);
  if ((tid & 63) == 0) sD[tid >> 6] = z;
  __syncthreads();
  if (tid == 0){
    double zz = 0.0; for (int w = 0; w < TPB/64; ++w) zz += sD[w];
    sliceM[b*SLICES + sl] = sMax;
    sliceZ[b*SLICES + sl] = zz;
  }
}

__global__ void k_combine(const float* __restrict__ temps, const float* sliceM,
                          const double* sliceZ, RowWS* rows){
  int b = blockIdx.x;
  if (threadIdx.x) return;
  float T = temps[b];
  float M = sliceM[b*SLICES];
  for (int s = 1; s < SLICES; ++s) M = fmaxf(M, sliceM[b*SLICES + s]);
  float A = M / T;
  double Z = 0.0;
  for (int s = 0; s < SLICES; ++s)
    Z += sliceZ[b*SLICES + s] * exp((double)(sliceM[b*SLICES + s] / T) - (double)A);
  rows[b].A = A; rows[b].Zf = (float)Z;
}

// ---- pass 2: compute K once, cache to Kc, build L1 histogram ----
__global__ __launch_bounds__(TPB) void k_l1hist(const float* __restrict__ logits,
    const float* __restrict__ temps, const RowWS* __restrict__ rows,
    double* L1S, unsigned* L1C, unsigned* __restrict__ Kc){
  __shared__ double   hS[4*NB1];
  __shared__ unsigned hC[4*NB1];
  int blk = blockIdx.x, b = blk >> 3, sl = blk & 7, tid = threadIdx.x;
  int cp = (tid >> 6) & 3;
  for (int i = tid; i < 4*NB1; i += TPB){ hS[i] = 0.0; hC[i] = 0u; }
  float T = temps[b], A = rows[b].A, Zf = rows[b].Zf;
  __syncthreads();
  size_t base = (size_t)b*Vn + sl*SLICE_LEN;
  const float4* l4 = (const float4*)(logits + base);
  uint4* K4 = (uint4*)(Kc + base);
  for (int j = tid; j < SLICE_LEN/4; j += TPB){
    float4 v = l4[j];
    uint4 kk;
    float p0 = expf(v.x/T - A) / Zf; kk.x = __float_as_uint(p0);
    float p1 = expf(v.y/T - A) / Zf; kk.y = __float_as_uint(p1);
    float p2 = expf(v.z/T - A) / Zf; kk.z = __float_as_uint(p2);
    float p3 = expf(v.w/T - A) / Zf; kk.w = __float_as_uint(p3);
    unsigned b0 = min(kk.x >> 21, NB1-1u), b1 = min(kk.y >> 21, NB1-1u);
    unsigned b2 = min(kk.z >> 21, NB1-1u), b3 = min(kk.w >> 21, NB1-1u);
    unsafeAtomicAdd(&hS[cp*NB1 + b0], (double)p0); atomicAdd(&hC[cp*NB1 + b0], 1u);
    unsafeAtomicAdd(&hS[cp*NB1 + b1], (double)p1); atomicAdd(&hC[cp*NB1 + b1], 1u);
    unsafeAtomicAdd(&hS[cp*NB1 + b2], (double)p2); atomicAdd(&hC[cp*NB1 + b2], 1u);
    unsafeAtomicAdd(&hS[cp*NB1 + b3], (double)p3); atomicAdd(&hC[cp*NB1 + b3], 1u);
    K4[j] = kk;
  }
  __syncthreads();
  for (int bin = tid; bin < NB1; bin += TPB){
    unsigned c = hC[bin] + hC[NB1+bin] + hC[2*NB1+bin] + hC[3*NB1+bin];
    if (c){
      double s = hS[bin] + hS[NB1+bin] + hS[2*NB1+bin] + hS[3*NB1+bin];
      unsafeAtomicAdd(&L1S[(size_t)b*NB1 + bin], s);
      atomicAdd(&L1C[(size_t)b*NB1 + bin], c);
    }
  }
}

// ---- parallel L1 walk: suffix scan + argmax predicate ----
__global__ __launch_bounds__(WTPB) void k_l1walk(RowWS* rows, const double* L1S, const unsigned* L1C,
    const int* __restrict__ top_ks, const float* __restrict__ top_ps,
    const float* __restrict__ top_ps2, const float* __restrict__ min_ps){
  __shared__ double   sS[NB1+1];
  __shared__ unsigned sC[NB1+1];
  __shared__ int mx0, mx1, mx2, mnz;
  int b = blockIdx.x, t = threadIdx.x;
  RowWS& R = rows[b];
  if (t == 0){ sS[NB1] = 0.0; sC[NB1] = 0u; mx0 = -1; mx1 = -1; mx2 = -1; mnz = NB1; }
  unsigned c = L1C[(size_t)b*NB1 + t];
  double   s = L1S[(size_t)b*NB1 + t];
  sS[t] = s; sC[t] = c;
  __syncthreads();
  for (int off = 1; off < NB1; off <<= 1){
    double   vs = sS[t] + ((t+off < NB1) ? sS[t+off] : 0.0);
    unsigned vc = sC[t] + ((t+off < NB1) ? sC[t+off] : 0u);
    __syncthreads();
    sS[t] = vs; sC[t] = vc;
    __syncthreads();
  }
  float Zf = R.Zf;
  float thr = (1.0f / Zf) * min_ps[b];
  unsigned thrBits = __float_as_uint(thr);
  int thrBin = (int)(thrBits >> 21); if (thrBin > NB1-1) thrBin = NB1-1;
  unsigned k = (unsigned)top_ks[b];
  double tauP = (double)top_ps[b], tauP2 = (double)top_ps2[b];
  if (c){
    if (sC[t] >= k)    atomicMax(&mx0, t);
    if (sS[t] > tauP ) atomicMax(&mx1, t);
    if (sS[t] > tauP2) atomicMax(&mx2, t);
    atomicMin(&mnz, t);
  }
  __syncthreads();
  unsigned Cexc = sC[t+1]; double Sexc = sS[t+1];
  if (t == 0) R.thrBits = thrBits;
  if (t == thrBin){ R.cutBin[3] = (unsigned)t; R.Cbef[3] = Cexc; R.Sbef[3] = Sexc; }
  int w0 = mx0;                                 // always exists (total count >= k)
  int w1 = (mx1 >= 0) ? mx1 : mnz;
  int w2 = (mx2 >= 0) ? mx2 : mnz;
  if (t == w0){ R.cutBin[0] = (unsigned)t; R.Cbef[0] = Cexc; R.Sbef[0] = Sexc; }
  if (t == w1){ R.cutBin[1] = (unsigned)t; R.Cbef[1] = Cexc; R.Sbef[1] = Sexc; }
  if (t == w2){ R.cutBin[2] = (unsigned)t; R.Cbef[2] = Cexc; R.Sbef[2] = Sexc; }
}

// ---- pass 3: L2 histograms for q0..q3 ----
__global__ __launch_bounds__(TPB) void k_l2hist(const unsigned* __restrict__ Kc,
    const RowWS* __restrict__ rows, double* L2S, unsigned* L2C){
  __shared__ double   hS[4*NB2];
  __shared__ unsigned hC[4*NB2];
  int blk = blockIdx.x, b = blk >> 3, sl = blk & 7, tid = threadIdx.x;
  for (int i = tid; i < 4*NB2; i += TPB){ hS[i] = 0.0; hC[i] = 0u; }
  unsigned tb0 = rows[b].cutBin[0], tb1 = rows[b].cutBin[1];
  unsigned tb2 = rows[b].cutBin[2], tb3 = rows[b].cutBin[3];
  __syncthreads();
  const uint4* K4 = (const uint4*)(Kc + (size_t)b*Vn + sl*SLICE_LEN);
  for (int j = tid; j < SLICE_LEN/4; j += TPB){
    uint4 kk = K4[j];
    #pragma unroll
    for (int c = 0; c < 4; ++c){
      unsigned K = (c==0)?kk.x:(c==1)?kk.y:(c==2)?kk.z:kk.w;
      unsigned bin = K >> 21, sub = (K >> 12) & (NB2-1);
      double p = (double)__uint_as_float(K);
      if (bin == tb0){ unsafeAtomicAdd(&hS[0*NB2+sub], p); atomicAdd(&hC[0*NB2+sub], 1u); }
      if (bin == tb1){ unsafeAtomicAdd(&hS[1*NB2+sub], p); atomicAdd(&hC[1*NB2+sub], 1u); }
      if (bin == tb2){ unsafeAtomicAdd(&hS[2*NB2+sub], p); atomicAdd(&hC[2*NB2+sub], 1u); }
      if (bin == tb3){ unsafeAtomicAdd(&hS[3*NB2+sub], p); atomicAdd(&hC[3*NB2+sub], 1u); }
    }
  }
  __syncthreads();
  for (int i = tid; i < 4*NB2; i += TPB){
    if (hC[i]){
      unsafeAtomicAdd(&L2S[((size_t)b*5)*NB2 + i], hS[i]);
      atomicAdd(&L2C[((size_t)b*5)*NB2 + i], hC[i]);
    }
  }
}

// ---- parallel L2 walk: one block per (row, query) ----
__global__ __launch_bounds__(WTPB) void k_l2walk(RowWS* rows, const double* L2S, const unsigned* L2C,
    const int* __restrict__ top_ks, const float* __restrict__ top_ps,
    const float* __restrict__ top_ps2){
  __shared__ double   sS[NB2+1];
  __shared__ unsigned sC[NB2+1];
  __shared__ int mx, mnz;
  __shared__ unsigned snapC, snapCut, snapThr;
  __shared__ double snapS;
  int b = blockIdx.x >> 2, q = blockIdx.x & 3, t = threadIdx.x;
  RowWS& R = rows[b];
  if (t == 0){
    sS[NB2] = 0.0; sC[NB2] = 0u; mx = -1; mnz = NB2;
    snapC = R.Cbef[q]; snapS = R.Sbef[q]; snapCut = R.cutBin[q]; snapThr = R.thrBits;
  }
  unsigned c = L2C[((size_t)b*5+q)*NB2 + t];
  double   s = L2S[((size_t)b*5+q)*NB2 + t];
  sS[t] = s; sC[t] = c;
  __syncthreads();
  for (int off = 1; off < NB2; off <<= 1){
    double   vs = sS[t] + ((t+off < NB2) ? sS[t+off] : 0.0);
    unsigned vc = sC[t] + ((t+off < NB2) ? sC[t+off] : 0u);
    __syncthreads();
    sS[t] = vs; sC[t] = vc;
    __syncthreads();
  }
  unsigned baseC = snapC; double baseS = snapS; unsigned cutBin = snapCut;
  if (q == 3){
    int thrSub = (int)((snapThr >> 12) & (NB2-1));
    if (t == thrSub){
      R.cutPre[3] = (cutBin << 9) | (unsigned)t;
      R.Cbef[3] = baseC + sC[t+1];
      R.Sbef[3] = baseS + sS[t+1];
    }
    return;
  }
  unsigned k = (unsigned)top_ks[b];
  double tau = (q == 1) ? (double)top_ps[b] : (double)top_ps2[b];
  if (c){
    if (q == 0){ if (baseC + sC[t] >= k) atomicMax(&mx, t); }
    else       { if (baseS + sS[t] > tau) atomicMax(&mx, t); }
    atomicMin(&mnz, t);
  }
  __syncthreads();
  int w = (mx >= 0) ? mx : mnz;          // mnz < NB2 (cut bin is non-empty)
  if (t == w){
    R.cutPre[q] = (cutBin << 9) | (unsigned)t;
    R.Cbef[q] = baseC + sC[t+1];
    R.Sbef[q] = baseS + sS[t+1];
  }
}

// ---- pass 4: collect boundary candidates q0..q3 ----
__global__ __launch_bounds__(TPB) void k_collect(const unsigned* __restrict__ Kc,
    const RowWS* __restrict__ rows, unsigned long long* lists, unsigned* lcnt){
  int blk = blockIdx.x, b = blk >> 3, sl = blk & 7, tid = threadIdx.x;
  unsigned t0 = rows[b].cutPre[0], t1 = rows[b].cutPre[1];
  unsigned t2 = rows[b].cutPre[2], t3 = rows[b].cutPre[3];
  int base = sl*SLICE_LEN;
  const uint4* K4 = (const uint4*)(Kc + (size_t)b*Vn + base);
  for (int j = tid; j < SLICE_LEN/4; j += TPB){
    uint4 kk = K4[j];
    #pragma unroll
    for (int c = 0; c < 4; ++c){
      unsigned K = (c==0)?kk.x:(c==1)?kk.y:(c==2)?kk.z:kk.w;
      unsigned pre = K >> 12;
      if (pre != t0 && pre != t1 && pre != t2 && pre != t3) continue;
      int i = base + j*4 + c;
      unsigned long long e = (((unsigned long long)(~K)) << 32) | (unsigned)i;
      if (pre == t0){ unsigned pos = atomicAdd(&lcnt[b*8+0], 1u); if (pos < CAP) lists[((size_t)b*5+0)*CAP+pos] = e; }
      if (pre == t1){ unsigned pos = atomicAdd(&lcnt[b*8+1], 1u); if (pos < CAP) lists[((size_t)b*5+1)*CAP+pos] = e; }
      if (pre == t2){ unsigned pos = atomicAdd(&lcnt[b*8+2], 1u); if (pos < CAP) lists[((size_t)b*5+2)*CAP+pos] = e; }
      if (pre == t3){ unsigned pos = atomicAdd(&lcnt[b*8+3], 1u); if (pos < CAP) lists[((size_t)b*5+3)*CAP+pos] = e; }
    }
  }
}

// ---- resolve boundaries (thread 0) + PARALLEL q4 L1 walk ----
__global__ __launch_bounds__(WTPB) void k_resolve(RowWS* rows, const unsigned long long* lists,
    const unsigned* lcnt, const double* L1S, const unsigned* L1C,
    const int* __restrict__ top_ks, const float* __restrict__ top_ps,
    const float* __restrict__ top_ps2, const float* __restrict__ uarr){
  __shared__ double   sS[NB1+1];
  __shared__ unsigned sC[NB1+1];
  __shared__ unsigned long long Ls[4*CAP];
  __shared__ int mx;
  __shared__ double sT4d;
  int b = blockIdx.x, t = threadIdx.x;
  RowWS& R = rows[b];
  int nq[4];
  for (int q = 0; q < 4; ++q){
    int n = (int)lcnt[b*8+q]; if (n > CAP) n = CAP; nq[q] = n;
    for (int j = t; j < n; j += WTPB) Ls[q*CAP+j] = lists[((size_t)b*5+q)*CAP + j];
  }
  if (t == 0){ sS[NB1] = 0.0; sC[NB1] = 0u; mx = -1; }
  unsigned c = L1C[(size_t)b*NB1 + t];
  double   s = L1S[(size_t)b*NB1 + t];
  sS[t] = s; sC[t] = c;
  __syncthreads();
  for (int off = 1; off < NB1; off <<= 1){
    double   vs = sS[t] + ((t+off < NB1) ? sS[t+off] : 0.0);
    unsigned vc = sC[t] + ((t+off < NB1) ? sC[t+off] : 0u);
    __syncthreads();
    sS[t] = vs; sC[t] = vc;
    __syncthreads();
  }
  if (t == 0){
    int k = top_ks[b];
    double tauP = (double)top_ps[b], tauP2 = (double)top_ps2[b];
    unsigned vS[4]; int iS[4]; double sk[4];
    for (int q = 0; q < 4; ++q){
      int n = nq[q];
      unsigned long long* L = &Ls[q*CAP];
      for (int i2 = 1; i2 < n; ++i2){
        unsigned long long key = L[i2]; int j = i2-1;
        while (j >= 0 && L[j] > key){ L[j+1] = L[j]; --j; }
        L[j+1] = key;
      }
      double S = R.Sbef[q];
      if (q == 0){
        if (n > 0){
          int mm = k - (int)R.Cbef[0]; if (mm < 1) mm = 1; if (mm > n) mm = n;
          for (int j = 0; j < mm; ++j){ unsigned K = ~(unsigned)(L[j] >> 32); S += (double)__uint_as_float(K); }
          unsigned long long e = L[mm-1];
          vS[0] = ~(unsigned)(e >> 32); iS[0] = (int)(unsigned)(e & 0xFFFFFFFFu); sk[0] = S;
        } else { vS[0] = 0u; iS[0] = 0x7FFFFFFF; sk[0] = S; }
      } else if (q < 3){
        double tau = (q == 1) ? tauP : tauP2;
        int last = -1;
        for (int j = 0; j < n; ++j){
          if (S > tau) break;
          unsigned K = ~(unsigned)(L[j] >> 32);
          S += (double)__uint_as_float(K); last = j;
        }
        if (n > 0){
          int pick = (last < 0) ? 0 : last;
          unsigned long long e = L[pick];
          vS[q] = ~(unsigned)(e >> 32); iS[q] = (int)(unsigned)(e & 0xFFFFFFFFu); sk[q] = S;
        } else { vS[q] = 0u; iS[q] = 0x7FFFFFFF; sk[q] = S; }
      } else {
        unsigned thrB = R.thrBits;
        for (int j = 0; j < n; ++j){
          unsigned K = ~(unsigned)(L[j] >> 32);
          if (K < thrB) break;
          S += (double)__uint_as_float(K);
        }
        vS[3] = thrB; iS[3] = 0x7FFFFFFF; sk[3] = S;
      }
    }
    unsigned v0 = vS[0]; int i0 = iS[0]; double tot = sk[0];
    if (vS[1] > v0 || (vS[1] == v0 && iS[1] < i0)){ v0 = vS[1]; i0 = iS[1]; tot = sk[1]; }
    if (vS[3] > v0 || (vS[3] == v0 && iS[3] < i0)){ v0 = vS[3]; i0 = iS[3]; tot = sk[3]; }
    R.v0 = v0; R.i0 = i0;
    R.v2 = vS[2]; R.i2 = iS[2]; R.S2f = (float)sk[2];
    float t4 = uarr[b] * (float)tot;
    R.t4 = t4;
    sT4d = (double)t4;
  }
  __syncthreads();
  double t4d = sT4d;
  if (c && sS[t] >= t4d) atomicMax(&mx, t);
  __syncthreads();
  int w = mx;
  if (w < 0){
    if (t == 0){ R.q4mode = 2; R.token = R.i0; }
  } else {
    if (t == 0) R.q4mode = 0;
    if (t == w){ R.cutBin[4] = (unsigned)t; R.Cbef[4] = sC[t+1]; R.Sbef[4] = sS[t+1]; }
  }
}

// ---- pass 5: q4 L2 histogram ----
__global__ __launch_bounds__(TPB) void k_q4hist(const unsigned* __restrict__ Kc,
    const RowWS* __restrict__ rows, double* L2S, unsigned* L2C){
  __shared__ double   hS[NB2];
  __shared__ unsigned hC[NB2];
  int blk = blockIdx.x, b = blk >> 3, sl = blk & 7, tid = threadIdx.x;
  if (rows[b].q4mode == 2) return;
  for (int i = tid; i < NB2; i += TPB){ hS[i] = 0.0; hC[i] = 0u; }
  unsigned tb = rows[b].cutBin[4];
  __syncthreads();
  const uint4* K4 = (const uint4*)(Kc + (size_t)b*Vn + sl*SLICE_LEN);
  for (int j = tid; j < SLICE_LEN/4; j += TPB){
    uint4 kk = K4[j];
    #pragma unroll
    for (int c = 0; c < 4; ++c){
      unsigned K = (c==0)?kk.x:(c==1)?kk.y:(c==2)?kk.z:kk.w;
      if ((K >> 21) == tb){
        unsigned sub = (K >> 12) & (NB2-1);
        unsafeAtomicAdd(&hS[sub], (double)__uint_as_float(K)); atomicAdd(&hC[sub], 1u);
      }
    }
  }
  __syncthreads();
  for (int i = tid; i < NB2; i += TPB){
    if (hC[i]){
      unsafeAtomicAdd(&L2S[((size_t)b*5 + 4)*NB2 + i], hS[i]);
      atomicAdd(&L2C[((size_t)b*5 + 4)*NB2 + i], hC[i]);
    }
  }
}

// ---- parallel q4 L2 walk ----
__global__ __launch_bounds__(WTPB) void k_q4walk(RowWS* rows, const double* L2S, const unsigned* L2C){
  __shared__ double   sS[NB2+1];
  __shared__ unsigned sC[NB2+1];
  __shared__ int mx, mnz;
  __shared__ unsigned snapC, snapCut;
  __shared__ double snapS, snapT4;
  int b = blockIdx.x, t = threadIdx.x;
  RowWS& R = rows[b];
  if (R.q4mode == 2) return;     // uniform
  if (t == 0){
    sS[NB2] = 0.0; sC[NB2] = 0u; mx = -1; mnz = NB2;
    snapC = R.Cbef[4]; snapS = R.Sbef[4]; snapCut = R.cutBin[4]; snapT4 = (double)R.t4;
  }
  unsigned c = L2C[((size_t)b*5+4)*NB2 + t];
  double   s = L2S[((size_t)b*5+4)*NB2 + t];
  sS[t] = s; sC[t] = c;
  __syncthreads();
  for (int off = 1; off < NB2; off <<= 1){
    double   vs = sS[t] + ((t+off < NB2) ? sS[t+off] : 0.0);
    unsigned vc = sC[t] + ((t+off < NB2) ? sC[t+off] : 0u);
    __syncthreads();
    sS[t] = vs; sC[t] = vc;
    __syncthreads();
  }
  double baseS = snapS, t4d = snapT4;
  if (c){
    if (baseS + sS[t] >= t4d) atomicMax(&mx, t);
    atomicMin(&mnz, t);
  }
  __syncthreads();
  int w = (mx >= 0) ? mx : ((mnz < NB2) ? mnz : -1);
  if (w < 0){
    if (t == 0){ R.q4mode = 2; R.token = R.i0; }
  } else if (t == w){
    R.cutPre[4] = (snapCut << 9) | (unsigned)t;
    R.Cbef[4] = snapC + sC[t+1];
    R.Sbef[4] = snapS + sS[t+1];
  }
}

// ---- pass 6: write logprobs (in-place over Kc) + collect q4 candidates ----
__global__ __launch_bounds__(TPB) void k_out2(const RowWS* __restrict__ rows,
    unsigned long long* lists, unsigned* lcnt, float* __restrict__ outLp){
  int blk = blockIdx.x, b = blk >> 3, sl = blk & 7, tid = threadIdx.x;
  unsigned v2 = rows[b].v2; int i2 = rows[b].i2; float S2f = rows[b].S2f;
  bool doColl = (rows[b].q4mode == 0);
  unsigned t4p = rows[b].cutPre[4];
  int base = sl*SLICE_LEN;
  float4* O4 = (float4*)(outLp + (size_t)b*Vn + base);
  const uint4* K4 = (const uint4*)O4;   // aliased: read K, write logprob
  for (int j = tid; j < SLICE_LEN/4; j += TPB){
    uint4 kk = K4[j];
    float4 o;
    #pragma unroll
    for (int c = 0; c < 4; ++c){
      unsigned K = (c==0)?kk.x:(c==1)?kk.y:(c==2)?kk.z:kk.w;
      int i = base + j*4 + c;
      if (doColl && (K >> 12) == t4p){
        unsigned pos = atomicAdd(&lcnt[b*8+4], 1u);
        if (pos < CAP) lists[((size_t)b*5+4)*CAP + pos] = (((unsigned long long)(~K)) << 32) | (unsigned)i;
      }
      float p = __uint_as_float(K);
      float val = (K > v2 || (K == v2 && i <= i2)) ? fmaxf(logf(p / S2f), FMINV) : FOUT;
      if (c==0) o.x = val; else if (c==1) o.y = val; else if (c==2) o.z = val; else o.w = val;
    }
    O4[j] = o;
  }
}

// ---- final: pick token, write scalar outputs ----
__global__ void k_pick(RowWS* rows, const unsigned long long* lists, const unsigned* lcnt,
                       float* __restrict__ outTok, float* __restrict__ outNtlp){
  __shared__ unsigned long long Ls[CAP];
  int b = blockIdx.x, tid = threadIdx.x;
  RowWS& R = rows[b];
  int n = (int)lcnt[b*8+4]; if (n > CAP) n = CAP;
  if (R.q4mode != 2)
    for (int j = tid; j < n; j += 64) Ls[j] = lists[((size_t)b*5+4)*CAP + j];
  __syncthreads();
  if (tid) return;
  int token; unsigned pB;
  if (R.q4mode == 2){ token = R.token; pB = R.v0; }
  else {
    for (int i2 = 1; i2 < n; ++i2){
      unsigned long long key = Ls[i2]; int j = i2-1;
      while (j >= 0 && Ls[j] > key){ Ls[j+1] = Ls[j]; --j; }
      Ls[j+1] = key;
    }
    double S = R.Sbef[4], t4d = (double)R.t4;
    unsigned v0 = R.v0; int i0 = R.i0;
    token = -1; pB = R.v0;
    for (int j = 0; j < n; ++j){
      unsigned K = ~(unsigned)(Ls[j] >> 32);
      int idx = (int)(unsigned)(Ls[j] & 0xFFFFFFFFu);
      bool kept = (K > v0) || (K == v0 && idx <= i0);
      if (!kept){ token = i0; pB = v0; break; }
      S += (double)__uint_as_float(K);
      if (S >= t4d){ token = idx; pB = K; break; }
    }
    if (token < 0){ token = i0; pB = v0; }
  }
  unsigned v2 = R.v2; int i2 = R.i2;
  bool kept2 = (pB > v2) || (pB == v2 && token <= i2);
  float pt = __uint_as_float(pB);
  float lp = kept2 ? fmaxf(logf(pt / R.S2f), FMINV) : FOUT;
  outTok[b] = (float)token;
  outNtlp[b] = lp;
}

extern "C" void kernel_launch(void* const* d_in, const int* in_sizes, int n_in,
                              void* d_out, int out_size, void* d_ws, size_t ws_size,
                              hipStream_t stream)
{
  const float* logits  = (const float*)d_in[0];
  const float* temps   = (const float*)d_in[1];
  const int*   top_ks  = (const int*)d_in[2];
  const float* top_ps  = (const float*)d_in[3];
  const float* top_ps2 = (const float*)d_in[4];
  const float* min_ps  = (const float*)d_in[5];
  const float* uarr    = (const float*)d_in[6];

  char* ws = (char*)d_ws;
  RowWS*    rows   = (RowWS*)(ws + OFF_ROWS);
  float*    sliceM = (float*)(ws + OFF_SLICEM);
  double*   sliceZ = (double*)(ws + OFF_SLICEZ);
  double*   L1S    = (double*)(ws + OFF_L1S);
  unsigned* L1C    = (unsigned*)(ws + OFF_L1C);
  double*   L2S    = (double*)(ws + OFF_L2S);
  unsigned* L2C    = (unsigned*)(ws + OFF_L2C);
  unsigned* lcnt   = (unsigned*)(ws + OFF_LCNT);
  unsigned long long* lists = (unsigned long long*)(ws + OFF_LISTS);

  float* outTok  = (float*)d_out;
  float* outLp   = outTok + Bn;
  float* outNtlp = outLp + (size_t)Bn * Vn;
  unsigned* Kc   = (unsigned*)outLp;     // K-cache lives in the big output buffer

  const int G = Bn * SLICES;
  k_zero    <<<1024, TPB, 0, stream>>>((unsigned long long*)ws);
  k_maxz    <<<G,    TPB, 0, stream>>>(logits, temps, sliceM, sliceZ);
  k_combine <<<Bn,   64,  0, stream>>>(temps, sliceM, sliceZ, rows);
  k_l1hist  <<<G,    TPB, 0, stream>>>(logits, temps, rows, L1S, L1C, Kc);
  k_l1walk  <<<Bn,   WTPB, 0, stream>>>(rows, L1S, L1C, top_ks, top_ps, top_ps2, min_ps);
  k_l2hist  <<<G,    TPB, 0, stream>>>(Kc, rows, L2S, L2C);
  k_l2walk  <<<Bn*4, WTPB, 0, stream>>>(rows, L2S, L2C, top_ks, top_ps, top_ps2);
  k_collect <<<G,    TPB, 0, stream>>>(Kc, rows, lists, lcnt);
  k_resolve <<<Bn,   WTPB, 0, stream>>>(rows, lists, lcnt, L1S, L1C, top_ks, top_ps, top_ps2, uarr);
  k_q4hist  <<<G,    TPB, 0, stream>>>(Kc, rows, L2S, L2C);
  k_q4walk  <<<Bn,   WTPB, 0, stream>>>(rows, L2S, L2C);
  k_out2    <<<G,    TPB, 0, stream>>>(rows, lists, lcnt, outLp);
  k_pick    <<<Bn,   64,  0, stream>>>(rows, lists, lcnt, outTok, outNtlp);
}